// Round 17
// baseline (175.247 us; speedup 1.0000x reference)
//
#include <hip/hip_runtime.h>

// HMM forward via chunked parallel scan, EMISSION FUSED INTO SCAN:
// B=64, T=2048, N=64, D=128.  CHUNK LENGTH 32 (64 chunks/batch) for 8 waves/SIMD.
//
// Math: alpha_t = diag(e_t) * A^T * alpha_{t-1},  e_t[j] = exp(lb_t[j] - m_t).
// fused_scan block (b,cch) [128 thr = 2 waves]:
//   Phase A: wave J computes lb[rows 0..31][states 32J..32J+31] via 16 bf16
//     MFMA (Wc B-frags from global WBF); per-row max combined across the two
//     waves through LDS; e-tile -> LDS (bf16, scan layout) + MV (f32, global).
//     Chunk 63's spare row (t=2048) computes t=0 -> E0G (f32) for fwd2.
//   Phase B: r12-proven bf16 scan (32 steps): state = 4 bf16 B-frags; per step
//     a = A^T x b (8 asm MFMA, literal-0 C); b' = pack(a*e) fused in cvt_pk;
//     renorm every 8 steps (exact, absorbed into per-half Ls).
// fwd2: per batch fold 64 chunk matrices (G prefetched 1 ahead); per-half
//   scales combined exactly.
//
// B-fragment layout: lane (h=l>>5, il=l&31), frag Kb, word w, half q holds
// B[k][n] with k = 16*Kb + 8*h + 2*w + q, n = 32*J + il.
//
// ws layout (float units):
//   ATF  0        2048     A^T MFMA A-frags (bf16 pairs)
//   PI   2048     64       exp(log_softmax(priors))
//   CN   2112     64       -0.5*(t3 + D*log2pi)
//   WBF  2176     8192     emis Wc B-frags (bf16)
//   MV   10368    131072   m_t per (b,t)
//   PART 141440   64       per-batch final logsumexp
//   GLS  141504   8192     log-scale per (job, J-half)
//   E0G  149696   4096     e at t=0 per batch (f32)
//   G    153792   4194304  (= 8388608 bf16) chunk mats [job][new k][start n]
// total 4348096 floats = 17.4 MB

constexpr int ATF_OFF  = 0;
constexpr int PI_OFF   = 2048;
constexpr int CN_OFF   = 2112;
constexpr int WBF_OFF  = 2176;
constexpr int MV_OFF   = 10368;
constexpr int PART_OFF = 141440;
constexpr int GLS_OFF  = 141504;
constexpr int E0G_OFF  = 149696;
constexpr int G_OFF    = 153792;

typedef __attribute__((ext_vector_type(8))) short bf16x8;
typedef __attribute__((ext_vector_type(16))) float f32x16;

union BU { unsigned u[4]; bf16x8 v; };

__device__ inline float wave_max(float v) {
  #pragma unroll
  for (int off = 1; off < 64; off <<= 1) v = fmaxf(v, __shfl_xor(v, off));
  return v;
}
__device__ inline float wave_sum(float v) {
  #pragma unroll
  for (int off = 1; off < 64; off <<= 1) v += __shfl_xor(v, off);
  return v;
}
__device__ inline float read_lane(float v, int l) {
  return __uint_as_float(__builtin_amdgcn_readlane(__float_as_uint(v), l));
}
__device__ inline unsigned f2bf(float f) {   // RNE f32->bf16
  unsigned u = __float_as_uint(f);
  u += 0x7FFFu + ((u >> 16) & 1u);
  return u >> 16;
}
__device__ inline unsigned cvt_pk(float lo, float hi) {  // packed f32x2 -> bf16x2
  unsigned r;
  asm("v_cvt_pk_bf16_f32 %0, %1, %2" : "=v"(r) : "v"(lo), "v"(hi));
  return r;
}

// ---------------- setup (merged): blk0 = P/ATF/PI, blk1-8 = WBF, blk9 = CN ----------------
__global__ void setup_kernel(const float* __restrict__ trans,
                             const float* __restrict__ priors,
                             const float* __restrict__ means,
                             const float* __restrict__ log_vars,
                             float* __restrict__ ws) {
  __shared__ float Psh[64 * 64];
  int tid = threadIdx.x, blk = blockIdx.x;

  if (blk == 0) {
    int lane = tid & 63, w = tid >> 6;
    for (int r = 0; r < 16; ++r) {
      int i = w * 16 + r;
      float x = trans[i * 64 + lane];
      float m = wave_max(x);
      float s = wave_sum(__expf(x - m));
      Psh[i * 64 + lane] = __expf(x - (m + __logf(s)));
    }
    if (w == 0) {
      float x = priors[lane];
      float m = wave_max(x);
      float s = wave_sum(__expf(x - m));
      ws[PI_OFF + lane] = __expf(x - (m + __logf(s)));
    }
    __syncthreads();
    // ATF: A-operand frags of A^T, frag f = I*4+Kb; lane l holds
    // A_op[m=32I+(l&31)][k=16Kb+8(l>>5)+j] = P[k][m], j=0..7 packed pairs.
    for (int idx = tid; idx < 512; idx += 256) {
      int f = idx >> 6, l = idx & 63;
      int I = f >> 2, Kb = f & 3;
      int m = 32 * I + (l & 31);
      int kb = 16 * Kb + 8 * (l >> 5);
      unsigned u[4];
      #pragma unroll
      for (int p = 0; p < 4; ++p) {
        unsigned a = f2bf(Psh[(kb + 2 * p) * 64 + m]);
        unsigned b = f2bf(Psh[(kb + 2 * p + 1) * 64 + m]);
        u[p] = a | (b << 16);
      }
      *reinterpret_cast<uint4*>(&ws[ATF_OFF + idx * 4]) = make_uint4(u[0], u[1], u[2], u[3]);
    }
  } else if (blk <= 8) {
    // WBF: B-fragments of Wc. frag (Kb,J), lane l holds
    // B[k=16Kb+8(l>>5)+j][n=32J+(l&31)], j=0..7 packed pairs (even lo).
    int idx = (blk - 1) * 256 + tid;      // 0..2047
    int f = idx >> 6, l = idx & 63;
    int Kb = f >> 1, J = f & 1;
    int n = 32 * J + (l & 31);
    int kb = 16 * Kb + 8 * (l >> 5);
    unsigned u[4];
    #pragma unroll
    for (int p = 0; p < 4; ++p) {
      int k0 = kb + 2 * p, k1 = k0 + 1;
      int d0 = k0 & 127, d1 = k1 & 127;
      float iv0 = __expf(-log_vars[n * 128 + d0]);
      float iv1 = __expf(-log_vars[n * 128 + d1]);
      float a  = (k0 < 128) ? (-0.5f * iv0) : (means[n * 128 + d0] * iv0);
      float bb = (k1 < 128) ? (-0.5f * iv1) : (means[n * 128 + d1] * iv1);
      u[p] = f2bf(a) | (f2bf(bb) << 16);
    }
    *reinterpret_cast<uint4*>(&ws[WBF_OFF + idx * 4]) = make_uint4(u[0], u[1], u[2], u[3]);
  } else {
    // CN: cn[n] = -0.5*(sum_d (mu^2*iv + lv) + D*log(2pi)), 4-way over d
    float* part = Psh;
    int n = tid & 63, g = tid >> 6;
    float s = 0.f;
    for (int d = 32 * g; d < 32 * g + 32; ++d) {
      float lv = log_vars[n * 128 + d];
      float mu = means[n * 128 + d];
      s += mu * mu * __expf(-lv) + lv;
    }
    part[g * 64 + n] = s;
    __syncthreads();
    if (tid < 64) {
      float tot = (part[tid] + part[64 + tid]) + (part[128 + tid] + part[192 + tid]);
      ws[CN_OFF + tid] = -0.5f * (tot + 128.0f * 1.8378770664093453f);
    }
  }
}

// ---------------- fused: emission (phase A) + chunk scan (phase B), CLEN=32 ----------------
__global__ __launch_bounds__(128, 6) void fused_scan(const float* __restrict__ X,
                                                     float* __restrict__ ws) {
  __shared__ __align__(16) unsigned short Esh[32 * 64];   // 4 KB e-tile [row][state] bf16
  __shared__ float Mrow[2][32];                           // per-half row maxes

  const int tid = threadIdx.x;
  const int lane = tid & 63, J = tid >> 6;   // J = wave id = state half
  const int h = lane >> 5, il = lane & 31;
  const int job = blockIdx.x, b = job >> 6, cch = job & 63;
  const int tstart = 1 + cch * 32;
  const int len = (cch == 63) ? 31 : 32;

  // ================= phase A: emissions, rows 0..31, states 32J..32J+31 =================
  {
    int t_lane = tstart + il;                       // lane's t-row
    if (cch == 63 && il == 31) t_lane = 0;          // spare slot computes t=0
    const float* Xr = X + ((size_t)b * 2048 + t_lane) * 128;

    bf16x8 ax[8], asq[8];
    #pragma unroll
    for (int s = 0; s < 8; ++s) {
      float4 v0 = *reinterpret_cast<const float4*>(Xr + s * 16 + 8 * h);
      float4 v1 = *reinterpret_cast<const float4*>(Xr + s * 16 + 8 * h + 4);
      BU bx, bq;
      bx.u[0] = cvt_pk(v0.x, v0.y); bx.u[1] = cvt_pk(v0.z, v0.w);
      bx.u[2] = cvt_pk(v1.x, v1.y); bx.u[3] = cvt_pk(v1.z, v1.w);
      bq.u[0] = cvt_pk(v0.x * v0.x, v0.y * v0.y);
      bq.u[1] = cvt_pk(v0.z * v0.z, v0.w * v0.w);
      bq.u[2] = cvt_pk(v1.x * v1.x, v1.y * v1.y);
      bq.u[3] = cvt_pk(v1.z * v1.z, v1.w * v1.w);
      ax[s] = bx.v; asq[s] = bq.v;
    }

    const uint4* wbf = reinterpret_cast<const uint4*>(&ws[WBF_OFF]);
    f32x16 acc;
    #pragma unroll
    for (int z = 0; z < 16; ++z) acc[z] = 0.f;
    #pragma unroll
    for (int Kb = 0; Kb < 8; ++Kb) {
      BU bb;
      *reinterpret_cast<uint4*>(bb.u) = wbf[(2 * Kb + J) * 64 + lane];
      acc = __builtin_amdgcn_mfma_f32_32x32x16_bf16(asq[Kb], bb.v, acc, 0, 0, 0);
    }
    #pragma unroll
    for (int Kb = 8; Kb < 16; ++Kb) {
      BU bb;
      *reinterpret_cast<uint4*>(bb.u) = wbf[(2 * Kb + J) * 64 + lane];
      acc = __builtin_amdgcn_mfma_f32_32x32x16_bf16(ax[Kb - 8], bb.v, acc, 0, 0, 0);
    }

    float cnv = ws[CN_OFF + 32 * J + il];
    // pass 1: per-half row maxes -> LDS
    #pragma unroll
    for (int e = 0; e < 16; ++e) {
      float v = acc[e] + cnv;
      float pm = v;
      #pragma unroll
      for (int off = 1; off < 32; off <<= 1) pm = fmaxf(pm, __shfl_xor(pm, off));
      int r = (e & 3) + 8 * (e >> 2) + 4 * h;
      if (il == 0) Mrow[J][r] = pm;
    }
    __syncthreads();
    // pass 2: combined max, exp, store
    float* MVp = &ws[MV_OFF] + (size_t)b * 2048;
    #pragma unroll
    for (int e = 0; e < 16; ++e) {
      float v = acc[e] + cnv;
      int r = (e & 3) + 8 * (e >> 2) + 4 * h;
      float mx = fmaxf(Mrow[0][r], Mrow[1][r]);
      float ev = __expf(v - mx);
      if (cch == 63 && r == 31) {               // t = 0 special row
        ws[E0G_OFF + b * 64 + 32 * J + il] = ev;
        if (il == 0 && J == 0) MVp[0] = mx;
      } else {
        Esh[r * 64 + 32 * J + il] = (unsigned short)f2bf(ev);
        if (il == 0 && J == 0) MVp[tstart + r] = mx;
      }
    }
  }
  __syncthreads();

  // ================= phase B: r12 scan over LDS e-tile (len steps) =================
  bf16x8 atf0, atf1, atf2, atf3, atf4, atf5, atf6, atf7;
  atf0 = *reinterpret_cast<const bf16x8*>(&ws[ATF_OFF + (0 * 64 + lane) * 4]);
  atf1 = *reinterpret_cast<const bf16x8*>(&ws[ATF_OFF + (1 * 64 + lane) * 4]);
  atf2 = *reinterpret_cast<const bf16x8*>(&ws[ATF_OFF + (2 * 64 + lane) * 4]);
  atf3 = *reinterpret_cast<const bf16x8*>(&ws[ATF_OFF + (3 * 64 + lane) * 4]);
  atf4 = *reinterpret_cast<const bf16x8*>(&ws[ATF_OFF + (4 * 64 + lane) * 4]);
  atf5 = *reinterpret_cast<const bf16x8*>(&ws[ATF_OFF + (5 * 64 + lane) * 4]);
  atf6 = *reinterpret_cast<const bf16x8*>(&ws[ATF_OFF + (6 * 64 + lane) * 4]);
  atf7 = *reinterpret_cast<const bf16x8*>(&ws[ATF_OFF + (7 * 64 + lane) * 4]);

  // identity B-fragments: frag Kb word p half q holds 1.0 iff
  // k = 16Kb+8h+2p+q == 32J+il
  bf16x8 bf0, bf1, bf2, bf3;
  {
    int js0 = 32 * J + il - 8 * h;
#define IDF(dst, Kb) { int js = js0 - 16 * (Kb); BU bu_;                      \
    _Pragma("unroll")                                                         \
    for (int p = 0; p < 4; ++p)                                               \
      bu_.u[p] = ((js >> 1) == p) ? ((js & 1) ? 0x3F800000u : 0x00003F80u) : 0u; \
    dst = bu_.v; }
    IDF(bf0, 0) IDF(bf1, 1) IDF(bf2, 2) IDF(bf3, 3)
#undef IDF
  }

  float Ls = 0.0f;

#define LOADE(dst, idx) {                                                     \
    const char* Ep_ = reinterpret_cast<const char*>(Esh) + (size_t)(idx) * 128; \
    _Pragma("unroll")                                                         \
    for (int q_ = 0; q_ < 4; ++q_) {                                          \
      dst[q_]     = *reinterpret_cast<const uint2*>(Ep_ + 16 * q_ + 8 * h);   \
      dst[4 + q_] = *reinterpret_cast<const uint2*>(Ep_ + 64 + 16 * q_ + 8 * h); \
    } }

  // scale for element z of tile I: row = 32I + (z&3)+8(z>>2)+4h
#define SX(W, z, I)                                                           \
  ({ uint2 u_ = W[4 * (I) + ((z) >> 2)];                                      \
     unsigned w_ = (((z) >> 1) & 1) ? u_.y : u_.x;                            \
     __uint_as_float(((z) & 1) ? (w_ & 0xFFFF0000u) : (w_ << 16)); })

  // repack with fused diag(e) scale
#define BBS(dst, At, p, I, W) {                                               \
    unsigned xe0 = cvt_pk((At)[8*(p)+0] * SX(W, 8*(p)+0, I),                  \
                          (At)[8*(p)+1] * SX(W, 8*(p)+1, I));                 \
    unsigned xe1 = cvt_pk((At)[8*(p)+2] * SX(W, 8*(p)+2, I),                  \
                          (At)[8*(p)+3] * SX(W, 8*(p)+3, I));                 \
    unsigned xo0 = cvt_pk((At)[8*(p)+4] * SX(W, 8*(p)+4, I),                  \
                          (At)[8*(p)+5] * SX(W, 8*(p)+5, I));                 \
    unsigned xo1 = cvt_pk((At)[8*(p)+6] * SX(W, 8*(p)+6, I),                  \
                          (At)[8*(p)+7] * SX(W, 8*(p)+7, I));                 \
    asm("v_permlane32_swap_b32 %0, %1" : "+v"(xe0), "+v"(xo0));               \
    asm("v_permlane32_swap_b32 %0, %1" : "+v"(xe1), "+v"(xo1));               \
    BU bu_; bu_.u[0] = xe0; bu_.u[1] = xe1; bu_.u[2] = xo0; bu_.u[3] = xo1;   \
    dst = bu_.v; }

  // MFMA via inline asm; head uses LITERAL 0 as C operand
#define MFMA_HEAD(d, A, B)                                                    \
    asm("v_mfma_f32_32x32x16_bf16 %0, %1, %2, 0"                              \
        : "=&v"(d) : "v"(A), "v"(B));
#define MFMA_ACC(d, A, B)                                                     \
    asm("v_mfma_f32_32x32x16_bf16 %0, %1, %2, %0"                             \
        : "+v"(d) : "v"(A), "v"(B));

#define STEP(EW, DO_RN) {                                                     \
    f32x16 a0, a1;                                                            \
    MFMA_HEAD(a0, atf0, bf0)                                                  \
    MFMA_HEAD(a1, atf4, bf0)                                                  \
    MFMA_ACC(a0, atf1, bf1)                                                   \
    MFMA_ACC(a1, atf5, bf1)                                                   \
    MFMA_ACC(a0, atf2, bf2)                                                   \
    MFMA_ACC(a1, atf6, bf2)                                                   \
    MFMA_ACC(a0, atf3, bf3)                                                   \
    MFMA_ACC(a1, atf7, bf3)                                                   \
    asm volatile("s_nop 7\n\ts_nop 7\n\ts_nop 3" : "+v"(a0), "+v"(a1));       \
    if (DO_RN) {                                                              \
      float mx = 0.f;                                                         \
      _Pragma("unroll")                                                       \
      for (int z = 0; z < 16; ++z) mx = fmaxf(mx, fmaxf(a0[z], a1[z]));       \
      mx = wave_max(mx);                                                      \
      float inv = 1.0f / mx;                                                  \
      Ls += __logf(mx);                                                       \
      _Pragma("unroll")                                                       \
      for (int z = 0; z < 16; ++z) { a0[z] *= inv; a1[z] *= inv; }            \
    }                                                                         \
    BBS(bf0, a0, 0, 0, EW) BBS(bf1, a0, 1, 0, EW)                             \
    BBS(bf2, a1, 0, 1, EW) BBS(bf3, a1, 1, 1, EW) }

  uint2 eA[8];
  #pragma unroll 1
  for (int step = 0; step < len; ++step) {
    LOADE(eA, step);
    STEP(eA, ((step & 7) == 7));
  }

#undef STEP
#undef MFMA_ACC
#undef MFMA_HEAD
#undef BBS
#undef SX
#undef LOADE

  // store G [new k][start n] directly from b-frags (k = 16Kb+8h+2p+q)
  unsigned short* Gb = reinterpret_cast<unsigned short*>(&ws[G_OFF]) + (size_t)job * 4096;
#define GST(fr, Kb) { BU bu_; bu_.v = fr;                                     \
    _Pragma("unroll")                                                         \
    for (int p = 0; p < 4; ++p) {                                             \
      int k = 16 * (Kb) + 8 * h + 2 * p;                                      \
      Gb[k * 64 + 32 * J + il]       = (unsigned short)(bu_.u[p] & 0xFFFFu);  \
      Gb[(k + 1) * 64 + 32 * J + il] = (unsigned short)(bu_.u[p] >> 16);      \
    } }
  GST(bf0, 0) GST(bf1, 1) GST(bf2, 2) GST(bf3, 3)
#undef GST
  if (lane == 0) ws[GLS_OFF + job * 2 + J] = Ls;
}

// ---------------- phase 2: fold 64 chunk matrices per batch (G prefetched) ----------------
__global__ __launch_bounds__(64, 1) void fwd2_combine(float* __restrict__ ws) {
  int b = blockIdx.x, j = threadIdx.x;

  float Ms = 0.f;
  for (int k = 0; k < 32; ++k) Ms += ws[MV_OFF + (size_t)b * 2048 + k * 64 + j];
  Ms = wave_sum(Ms);

  float w = ws[PI_OFF + j] * ws[E0G_OFF + b * 64 + j];   // alpha_0 modulo exp(m_0)
  float Lacc = Ms;

  const unsigned short* Gb =
      reinterpret_cast<const unsigned short*>(&ws[G_OFF]) + (size_t)b * 64 * 4096;
  const uint4* gbase = reinterpret_cast<const uint4*>(Gb);

  uint4 gw[8];
  #pragma unroll
  for (int s = 0; s < 8; ++s) gw[s] = gbase[j * 4 + s];

  for (int c = 0; c < 64; ++c) {
    uint4 gn[8];
    int cnx = (c + 1 < 64) ? (c + 1) : c;
    #pragma unroll
    for (int s = 0; s < 8; ++s) gn[s] = gbase[(size_t)cnx * 256 + j * 4 + s];

    float gv[64];
    #pragma unroll
    for (int s = 0; s < 8; ++s) {
      gv[8 * s + 0] = __uint_as_float(gw[s].x << 16);
      gv[8 * s + 1] = __uint_as_float(gw[s].x & 0xFFFF0000u);
      gv[8 * s + 2] = __uint_as_float(gw[s].y << 16);
      gv[8 * s + 3] = __uint_as_float(gw[s].y & 0xFFFF0000u);
      gv[8 * s + 4] = __uint_as_float(gw[s].z << 16);
      gv[8 * s + 5] = __uint_as_float(gw[s].z & 0xFFFF0000u);
      gv[8 * s + 6] = __uint_as_float(gw[s].w << 16);
      gv[8 * s + 7] = __uint_as_float(gw[s].w & 0xFFFF0000u);
    }
    // split fold: lo (start states 0-31, scale Ls0) / hi (32-63, Ls1)
    float l0 = 0.f, l1 = 0.f, h0 = 0.f, h1 = 0.f;
    #pragma unroll
    for (int i = 0; i < 32; i += 2) {
      l0 = fmaf(read_lane(w, i + 0), gv[i + 0], l0);
      l1 = fmaf(read_lane(w, i + 1), gv[i + 1], l1);
      h0 = fmaf(read_lane(w, 32 + i + 0), gv[32 + i + 0], h0);
      h1 = fmaf(read_lane(w, 32 + i + 1), gv[32 + i + 1], h1);
    }
    float ylo = l0 + l1, yhi = h0 + h1;
    float g0 = ws[GLS_OFF + (b * 64 + c) * 2 + 0];
    float g1 = ws[GLS_OFF + (b * 64 + c) * 2 + 1];
    float Lm = fmaxf(g0, g1);
    float y = __expf(g0 - Lm) * ylo + __expf(g1 - Lm) * yhi;
    float s = wave_sum(y);
    w = y * (1.0f / s);
    Lacc += Lm + __logf(s);

    #pragma unroll
    for (int s2 = 0; s2 < 8; ++s2) gw[s2] = gn[s2];
  }
  float S = wave_sum(w);
  if (j == 0) ws[PART_OFF + b] = Lacc + __logf(S);
}

// ---------------- final deterministic sum ----------------
__global__ void final_kernel(const float* __restrict__ part, float* __restrict__ out) {
  float v = part[threadIdx.x];
  float s = wave_sum(v);
  if (threadIdx.x == 0) out[0] = s;
}

extern "C" void kernel_launch(void* const* d_in, const int* in_sizes, int n_in,
                              void* d_out, int out_size, void* d_ws, size_t ws_size,
                              hipStream_t stream) {
  const float* X        = (const float*)d_in[0];
  const float* trans    = (const float*)d_in[1];
  const float* priors   = (const float*)d_in[2];
  const float* means    = (const float*)d_in[3];
  const float* log_vars = (const float*)d_in[4];
  float* ws  = (float*)d_ws;
  float* out = (float*)d_out;

  hipLaunchKernelGGL(setup_kernel, dim3(10), dim3(256), 0, stream,
                     trans, priors, means, log_vars, ws);
  hipLaunchKernelGGL(fused_scan, dim3(4096), dim3(128), 0, stream, X, ws);
  hipLaunchKernelGGL(fwd2_combine, dim3(64), dim3(64), 0, stream, ws);
  hipLaunchKernelGGL(final_kernel, dim3(1), dim3(64), 0, stream,
                     ws + PART_OFF, out);
}

// Round 18
// 151.983 us; speedup vs baseline: 1.1531x; 1.1531x over previous
//
#include <hip/hip_runtime.h>

// HMM forward via chunked parallel scan, EMISSION FUSED INTO SCAN:
// B=64, T=2048, N=64, D=128.  CHUNK LENGTH 32 (64 chunks/batch) for 8 waves/SIMD.
//
// Math: alpha_t = diag(e_t) * A^T * alpha_{t-1},  e_t[j] = exp(lb_t[j] - m_t).
// fused_scan block (b,cch) [128 thr = 2 waves]:
//   Phase A: wave J computes lb[rows 0..31][states 32J..32J+31] via 16 bf16
//     MFMA (Wc B-frags from global WBF); per-row max combined across the two
//     waves through LDS; e-tile -> LDS (bf16, scan layout) + MV (f32, global).
//     Chunk 63's spare row (t=2048) computes t=0 -> E0G (f32) for fwd2.
//   Phase B: r12-proven bf16 scan (32 steps): state = 4 bf16 B-frags; per step
//     a = A^T x b (8 asm MFMA, literal-0 C); b' = pack(a*e) fused in cvt_pk;
//     renorm every 8 steps (exact, absorbed into per-half Ls).
// fwd2: per batch fold 64 chunk matrices (G prefetched 1 ahead); per-half
//   scales combined exactly.
//
// NOTE launch_bounds(128,4): r17 used (128,6) -> 85-reg cap -> scratch spill
// (VGPR 40, WRITE_SIZE 90MB). (128,4) allows 128 regs; r16 compiled to 64 VGPR
// under this bound, and at 64 VGPR the HW can still co-schedule 8 waves/SIMD —
// the second arg is an allocator minimum, not a scheduler cap.
//
// B-fragment layout: lane (h=l>>5, il=l&31), frag Kb, word w, half q holds
// B[k][n] with k = 16*Kb + 8*h + 2*w + q, n = 32*J + il.
//
// ws layout (float units):
//   ATF  0        2048     A^T MFMA A-frags (bf16 pairs)
//   PI   2048     64       exp(log_softmax(priors))
//   CN   2112     64       -0.5*(t3 + D*log2pi)
//   WBF  2176     8192     emis Wc B-frags (bf16)
//   MV   10368    131072   m_t per (b,t)
//   PART 141440   64       per-batch final logsumexp
//   GLS  141504   8192     log-scale per (job, J-half)
//   E0G  149696   4096     e at t=0 per batch (f32)
//   G    153792   4194304  (= 8388608 bf16) chunk mats [job][new k][start n]
// total 4348096 floats = 17.4 MB

constexpr int ATF_OFF  = 0;
constexpr int PI_OFF   = 2048;
constexpr int CN_OFF   = 2112;
constexpr int WBF_OFF  = 2176;
constexpr int MV_OFF   = 10368;
constexpr int PART_OFF = 141440;
constexpr int GLS_OFF  = 141504;
constexpr int E0G_OFF  = 149696;
constexpr int G_OFF    = 153792;

typedef __attribute__((ext_vector_type(8))) short bf16x8;
typedef __attribute__((ext_vector_type(16))) float f32x16;

union BU { unsigned u[4]; bf16x8 v; };

__device__ inline float wave_max(float v) {
  #pragma unroll
  for (int off = 1; off < 64; off <<= 1) v = fmaxf(v, __shfl_xor(v, off));
  return v;
}
__device__ inline float wave_sum(float v) {
  #pragma unroll
  for (int off = 1; off < 64; off <<= 1) v += __shfl_xor(v, off);
  return v;
}
__device__ inline float read_lane(float v, int l) {
  return __uint_as_float(__builtin_amdgcn_readlane(__float_as_uint(v), l));
}
__device__ inline unsigned f2bf(float f) {   // RNE f32->bf16
  unsigned u = __float_as_uint(f);
  u += 0x7FFFu + ((u >> 16) & 1u);
  return u >> 16;
}
__device__ inline unsigned cvt_pk(float lo, float hi) {  // packed f32x2 -> bf16x2
  unsigned r;
  asm("v_cvt_pk_bf16_f32 %0, %1, %2" : "=v"(r) : "v"(lo), "v"(hi));
  return r;
}

// ---------------- setup (merged): blk0 = P/ATF/PI, blk1-8 = WBF, blk9 = CN ----------------
__global__ void setup_kernel(const float* __restrict__ trans,
                             const float* __restrict__ priors,
                             const float* __restrict__ means,
                             const float* __restrict__ log_vars,
                             float* __restrict__ ws) {
  __shared__ float Psh[64 * 64];
  int tid = threadIdx.x, blk = blockIdx.x;

  if (blk == 0) {
    int lane = tid & 63, w = tid >> 6;
    for (int r = 0; r < 16; ++r) {
      int i = w * 16 + r;
      float x = trans[i * 64 + lane];
      float m = wave_max(x);
      float s = wave_sum(__expf(x - m));
      Psh[i * 64 + lane] = __expf(x - (m + __logf(s)));
    }
    if (w == 0) {
      float x = priors[lane];
      float m = wave_max(x);
      float s = wave_sum(__expf(x - m));
      ws[PI_OFF + lane] = __expf(x - (m + __logf(s)));
    }
    __syncthreads();
    // ATF: A-operand frags of A^T, frag f = I*4+Kb; lane l holds
    // A_op[m=32I+(l&31)][k=16Kb+8(l>>5)+j] = P[k][m], j=0..7 packed pairs.
    for (int idx = tid; idx < 512; idx += 256) {
      int f = idx >> 6, l = idx & 63;
      int I = f >> 2, Kb = f & 3;
      int m = 32 * I + (l & 31);
      int kb = 16 * Kb + 8 * (l >> 5);
      unsigned u[4];
      #pragma unroll
      for (int p = 0; p < 4; ++p) {
        unsigned a = f2bf(Psh[(kb + 2 * p) * 64 + m]);
        unsigned b = f2bf(Psh[(kb + 2 * p + 1) * 64 + m]);
        u[p] = a | (b << 16);
      }
      *reinterpret_cast<uint4*>(&ws[ATF_OFF + idx * 4]) = make_uint4(u[0], u[1], u[2], u[3]);
    }
  } else if (blk <= 8) {
    // WBF: B-fragments of Wc. frag (Kb,J), lane l holds
    // B[k=16Kb+8(l>>5)+j][n=32J+(l&31)], j=0..7 packed pairs (even lo).
    int idx = (blk - 1) * 256 + tid;      // 0..2047
    int f = idx >> 6, l = idx & 63;
    int Kb = f >> 1, J = f & 1;
    int n = 32 * J + (l & 31);
    int kb = 16 * Kb + 8 * (l >> 5);
    unsigned u[4];
    #pragma unroll
    for (int p = 0; p < 4; ++p) {
      int k0 = kb + 2 * p, k1 = k0 + 1;
      int d0 = k0 & 127, d1 = k1 & 127;
      float iv0 = __expf(-log_vars[n * 128 + d0]);
      float iv1 = __expf(-log_vars[n * 128 + d1]);
      float a  = (k0 < 128) ? (-0.5f * iv0) : (means[n * 128 + d0] * iv0);
      float bb = (k1 < 128) ? (-0.5f * iv1) : (means[n * 128 + d1] * iv1);
      u[p] = f2bf(a) | (f2bf(bb) << 16);
    }
    *reinterpret_cast<uint4*>(&ws[WBF_OFF + idx * 4]) = make_uint4(u[0], u[1], u[2], u[3]);
  } else {
    // CN: cn[n] = -0.5*(sum_d (mu^2*iv + lv) + D*log(2pi)), 4-way over d
    float* part = Psh;
    int n = tid & 63, g = tid >> 6;
    float s = 0.f;
    for (int d = 32 * g; d < 32 * g + 32; ++d) {
      float lv = log_vars[n * 128 + d];
      float mu = means[n * 128 + d];
      s += mu * mu * __expf(-lv) + lv;
    }
    part[g * 64 + n] = s;
    __syncthreads();
    if (tid < 64) {
      float tot = (part[tid] + part[64 + tid]) + (part[128 + tid] + part[192 + tid]);
      ws[CN_OFF + tid] = -0.5f * (tot + 128.0f * 1.8378770664093453f);
    }
  }
}

// ---------------- fused: emission (phase A) + chunk scan (phase B), CLEN=32 ----------------
__global__ __launch_bounds__(128, 4) void fused_scan(const float* __restrict__ X,
                                                     float* __restrict__ ws) {
  __shared__ __align__(16) unsigned short Esh[32 * 64];   // 4 KB e-tile [row][state] bf16
  __shared__ float Mrow[2][32];                           // per-half row maxes

  const int tid = threadIdx.x;
  const int lane = tid & 63, J = tid >> 6;   // J = wave id = state half
  const int h = lane >> 5, il = lane & 31;
  const int job = blockIdx.x, b = job >> 6, cch = job & 63;
  const int tstart = 1 + cch * 32;
  const int len = (cch == 63) ? 31 : 32;

  // ================= phase A: emissions, rows 0..31, states 32J..32J+31 =================
  {
    int t_lane = tstart + il;                       // lane's t-row
    if (cch == 63 && il == 31) t_lane = 0;          // spare slot computes t=0
    const float* Xr = X + ((size_t)b * 2048 + t_lane) * 128;

    bf16x8 ax[8], asq[8];
    #pragma unroll
    for (int s = 0; s < 8; ++s) {
      float4 v0 = *reinterpret_cast<const float4*>(Xr + s * 16 + 8 * h);
      float4 v1 = *reinterpret_cast<const float4*>(Xr + s * 16 + 8 * h + 4);
      BU bx, bq;
      bx.u[0] = cvt_pk(v0.x, v0.y); bx.u[1] = cvt_pk(v0.z, v0.w);
      bx.u[2] = cvt_pk(v1.x, v1.y); bx.u[3] = cvt_pk(v1.z, v1.w);
      bq.u[0] = cvt_pk(v0.x * v0.x, v0.y * v0.y);
      bq.u[1] = cvt_pk(v0.z * v0.z, v0.w * v0.w);
      bq.u[2] = cvt_pk(v1.x * v1.x, v1.y * v1.y);
      bq.u[3] = cvt_pk(v1.z * v1.z, v1.w * v1.w);
      ax[s] = bx.v; asq[s] = bq.v;
    }

    const uint4* wbf = reinterpret_cast<const uint4*>(&ws[WBF_OFF]);
    f32x16 acc;
    #pragma unroll
    for (int z = 0; z < 16; ++z) acc[z] = 0.f;
    #pragma unroll
    for (int Kb = 0; Kb < 8; ++Kb) {
      BU bb;
      *reinterpret_cast<uint4*>(bb.u) = wbf[(2 * Kb + J) * 64 + lane];
      acc = __builtin_amdgcn_mfma_f32_32x32x16_bf16(asq[Kb], bb.v, acc, 0, 0, 0);
    }
    #pragma unroll
    for (int Kb = 8; Kb < 16; ++Kb) {
      BU bb;
      *reinterpret_cast<uint4*>(bb.u) = wbf[(2 * Kb + J) * 64 + lane];
      acc = __builtin_amdgcn_mfma_f32_32x32x16_bf16(ax[Kb - 8], bb.v, acc, 0, 0, 0);
    }

    float cnv = ws[CN_OFF + 32 * J + il];
    // pass 1: per-half row maxes -> LDS
    #pragma unroll
    for (int e = 0; e < 16; ++e) {
      float v = acc[e] + cnv;
      float pm = v;
      #pragma unroll
      for (int off = 1; off < 32; off <<= 1) pm = fmaxf(pm, __shfl_xor(pm, off));
      int r = (e & 3) + 8 * (e >> 2) + 4 * h;
      if (il == 0) Mrow[J][r] = pm;
    }
    __syncthreads();
    // pass 2: combined max, exp, store
    float* MVp = &ws[MV_OFF] + (size_t)b * 2048;
    #pragma unroll
    for (int e = 0; e < 16; ++e) {
      float v = acc[e] + cnv;
      int r = (e & 3) + 8 * (e >> 2) + 4 * h;
      float mx = fmaxf(Mrow[0][r], Mrow[1][r]);
      float ev = __expf(v - mx);
      if (cch == 63 && r == 31) {               // t = 0 special row
        ws[E0G_OFF + b * 64 + 32 * J + il] = ev;
        if (il == 0 && J == 0) MVp[0] = mx;
      } else {
        Esh[r * 64 + 32 * J + il] = (unsigned short)f2bf(ev);
        if (il == 0 && J == 0) MVp[tstart + r] = mx;
      }
    }
  }
  __syncthreads();

  // ================= phase B: r12 scan over LDS e-tile (len steps) =================
  bf16x8 atf0, atf1, atf2, atf3, atf4, atf5, atf6, atf7;
  atf0 = *reinterpret_cast<const bf16x8*>(&ws[ATF_OFF + (0 * 64 + lane) * 4]);
  atf1 = *reinterpret_cast<const bf16x8*>(&ws[ATF_OFF + (1 * 64 + lane) * 4]);
  atf2 = *reinterpret_cast<const bf16x8*>(&ws[ATF_OFF + (2 * 64 + lane) * 4]);
  atf3 = *reinterpret_cast<const bf16x8*>(&ws[ATF_OFF + (3 * 64 + lane) * 4]);
  atf4 = *reinterpret_cast<const bf16x8*>(&ws[ATF_OFF + (4 * 64 + lane) * 4]);
  atf5 = *reinterpret_cast<const bf16x8*>(&ws[ATF_OFF + (5 * 64 + lane) * 4]);
  atf6 = *reinterpret_cast<const bf16x8*>(&ws[ATF_OFF + (6 * 64 + lane) * 4]);
  atf7 = *reinterpret_cast<const bf16x8*>(&ws[ATF_OFF + (7 * 64 + lane) * 4]);

  // identity B-fragments: frag Kb word p half q holds 1.0 iff
  // k = 16Kb+8h+2p+q == 32J+il
  bf16x8 bf0, bf1, bf2, bf3;
  {
    int js0 = 32 * J + il - 8 * h;
#define IDF(dst, Kb) { int js = js0 - 16 * (Kb); BU bu_;                      \
    _Pragma("unroll")                                                         \
    for (int p = 0; p < 4; ++p)                                               \
      bu_.u[p] = ((js >> 1) == p) ? ((js & 1) ? 0x3F800000u : 0x00003F80u) : 0u; \
    dst = bu_.v; }
    IDF(bf0, 0) IDF(bf1, 1) IDF(bf2, 2) IDF(bf3, 3)
#undef IDF
  }

  float Ls = 0.0f;

#define LOADE(dst, idx) {                                                     \
    const char* Ep_ = reinterpret_cast<const char*>(Esh) + (size_t)(idx) * 128; \
    _Pragma("unroll")                                                         \
    for (int q_ = 0; q_ < 4; ++q_) {                                          \
      dst[q_]     = *reinterpret_cast<const uint2*>(Ep_ + 16 * q_ + 8 * h);   \
      dst[4 + q_] = *reinterpret_cast<const uint2*>(Ep_ + 64 + 16 * q_ + 8 * h); \
    } }

  // scale for element z of tile I: row = 32I + (z&3)+8(z>>2)+4h
#define SX(W, z, I)                                                           \
  ({ uint2 u_ = W[4 * (I) + ((z) >> 2)];                                      \
     unsigned w_ = (((z) >> 1) & 1) ? u_.y : u_.x;                            \
     __uint_as_float(((z) & 1) ? (w_ & 0xFFFF0000u) : (w_ << 16)); })

  // repack with fused diag(e) scale
#define BBS(dst, At, p, I, W) {                                               \
    unsigned xe0 = cvt_pk((At)[8*(p)+0] * SX(W, 8*(p)+0, I),                  \
                          (At)[8*(p)+1] * SX(W, 8*(p)+1, I));                 \
    unsigned xe1 = cvt_pk((At)[8*(p)+2] * SX(W, 8*(p)+2, I),                  \
                          (At)[8*(p)+3] * SX(W, 8*(p)+3, I));                 \
    unsigned xo0 = cvt_pk((At)[8*(p)+4] * SX(W, 8*(p)+4, I),                  \
                          (At)[8*(p)+5] * SX(W, 8*(p)+5, I));                 \
    unsigned xo1 = cvt_pk((At)[8*(p)+6] * SX(W, 8*(p)+6, I),                  \
                          (At)[8*(p)+7] * SX(W, 8*(p)+7, I));                 \
    asm("v_permlane32_swap_b32 %0, %1" : "+v"(xe0), "+v"(xo0));               \
    asm("v_permlane32_swap_b32 %0, %1" : "+v"(xe1), "+v"(xo1));               \
    BU bu_; bu_.u[0] = xe0; bu_.u[1] = xe1; bu_.u[2] = xo0; bu_.u[3] = xo1;   \
    dst = bu_.v; }

  // MFMA via inline asm; head uses LITERAL 0 as C operand
#define MFMA_HEAD(d, A, B)                                                    \
    asm("v_mfma_f32_32x32x16_bf16 %0, %1, %2, 0"                              \
        : "=&v"(d) : "v"(A), "v"(B));
#define MFMA_ACC(d, A, B)                                                     \
    asm("v_mfma_f32_32x32x16_bf16 %0, %1, %2, %0"                             \
        : "+v"(d) : "v"(A), "v"(B));

#define STEP(EW, DO_RN) {                                                     \
    f32x16 a0, a1;                                                            \
    MFMA_HEAD(a0, atf0, bf0)                                                  \
    MFMA_HEAD(a1, atf4, bf0)                                                  \
    MFMA_ACC(a0, atf1, bf1)                                                   \
    MFMA_ACC(a1, atf5, bf1)                                                   \
    MFMA_ACC(a0, atf2, bf2)                                                   \
    MFMA_ACC(a1, atf6, bf2)                                                   \
    MFMA_ACC(a0, atf3, bf3)                                                   \
    MFMA_ACC(a1, atf7, bf3)                                                   \
    asm volatile("s_nop 7\n\ts_nop 7\n\ts_nop 3" : "+v"(a0), "+v"(a1));       \
    if (DO_RN) {                                                              \
      float mx = 0.f;                                                         \
      _Pragma("unroll")                                                       \
      for (int z = 0; z < 16; ++z) mx = fmaxf(mx, fmaxf(a0[z], a1[z]));       \
      mx = wave_max(mx);                                                      \
      float inv = 1.0f / mx;                                                  \
      Ls += __logf(mx);                                                       \
      _Pragma("unroll")                                                       \
      for (int z = 0; z < 16; ++z) { a0[z] *= inv; a1[z] *= inv; }            \
    }                                                                         \
    BBS(bf0, a0, 0, 0, EW) BBS(bf1, a0, 1, 0, EW)                             \
    BBS(bf2, a1, 0, 1, EW) BBS(bf3, a1, 1, 1, EW) }

  uint2 eA[8];
  #pragma unroll 1
  for (int step = 0; step < len; ++step) {
    LOADE(eA, step);
    STEP(eA, ((step & 7) == 7));
  }

#undef STEP
#undef MFMA_ACC
#undef MFMA_HEAD
#undef BBS
#undef SX
#undef LOADE

  // store G [new k][start n] directly from b-frags (k = 16Kb+8h+2p+q)
  unsigned short* Gb = reinterpret_cast<unsigned short*>(&ws[G_OFF]) + (size_t)job * 4096;
#define GST(fr, Kb) { BU bu_; bu_.v = fr;                                     \
    _Pragma("unroll")                                                         \
    for (int p = 0; p < 4; ++p) {                                             \
      int k = 16 * (Kb) + 8 * h + 2 * p;                                      \
      Gb[k * 64 + 32 * J + il]       = (unsigned short)(bu_.u[p] & 0xFFFFu);  \
      Gb[(k + 1) * 64 + 32 * J + il] = (unsigned short)(bu_.u[p] >> 16);      \
    } }
  GST(bf0, 0) GST(bf1, 1) GST(bf2, 2) GST(bf3, 3)
#undef GST
  if (lane == 0) ws[GLS_OFF + job * 2 + J] = Ls;
}

// ---------------- phase 2: fold 64 chunk matrices per batch (G prefetched) ----------------
__global__ __launch_bounds__(64, 1) void fwd2_combine(float* __restrict__ ws) {
  int b = blockIdx.x, j = threadIdx.x;

  float Ms = 0.f;
  for (int k = 0; k < 32; ++k) Ms += ws[MV_OFF + (size_t)b * 2048 + k * 64 + j];
  Ms = wave_sum(Ms);

  float w = ws[PI_OFF + j] * ws[E0G_OFF + b * 64 + j];   // alpha_0 modulo exp(m_0)
  float Lacc = Ms;

  const unsigned short* Gb =
      reinterpret_cast<const unsigned short*>(&ws[G_OFF]) + (size_t)b * 64 * 4096;
  const uint4* gbase = reinterpret_cast<const uint4*>(Gb);

  uint4 gw[8];
  #pragma unroll
  for (int s = 0; s < 8; ++s) gw[s] = gbase[j * 4 + s];

  for (int c = 0; c < 64; ++c) {
    uint4 gn[8];
    int cnx = (c + 1 < 64) ? (c + 1) : c;
    #pragma unroll
    for (int s = 0; s < 8; ++s) gn[s] = gbase[(size_t)cnx * 256 + j * 4 + s];

    float gv[64];
    #pragma unroll
    for (int s = 0; s < 8; ++s) {
      gv[8 * s + 0] = __uint_as_float(gw[s].x << 16);
      gv[8 * s + 1] = __uint_as_float(gw[s].x & 0xFFFF0000u);
      gv[8 * s + 2] = __uint_as_float(gw[s].y << 16);
      gv[8 * s + 3] = __uint_as_float(gw[s].y & 0xFFFF0000u);
      gv[8 * s + 4] = __uint_as_float(gw[s].z << 16);
      gv[8 * s + 5] = __uint_as_float(gw[s].z & 0xFFFF0000u);
      gv[8 * s + 6] = __uint_as_float(gw[s].w << 16);
      gv[8 * s + 7] = __uint_as_float(gw[s].w & 0xFFFF0000u);
    }
    // split fold: lo (start states 0-31, scale Ls0) / hi (32-63, Ls1)
    float l0 = 0.f, l1 = 0.f, h0 = 0.f, h1 = 0.f;
    #pragma unroll
    for (int i = 0; i < 32; i += 2) {
      l0 = fmaf(read_lane(w, i + 0), gv[i + 0], l0);
      l1 = fmaf(read_lane(w, i + 1), gv[i + 1], l1);
      h0 = fmaf(read_lane(w, 32 + i + 0), gv[32 + i + 0], h0);
      h1 = fmaf(read_lane(w, 32 + i + 1), gv[32 + i + 1], h1);
    }
    float ylo = l0 + l1, yhi = h0 + h1;
    float g0 = ws[GLS_OFF + (b * 64 + c) * 2 + 0];
    float g1 = ws[GLS_OFF + (b * 64 + c) * 2 + 1];
    float Lm = fmaxf(g0, g1);
    float y = __expf(g0 - Lm) * ylo + __expf(g1 - Lm) * yhi;
    float s = wave_sum(y);
    w = y * (1.0f / s);
    Lacc += Lm + __logf(s);

    #pragma unroll
    for (int s2 = 0; s2 < 8; ++s2) gw[s2] = gn[s2];
  }
  float S = wave_sum(w);
  if (j == 0) ws[PART_OFF + b] = Lacc + __logf(S);
}

// ---------------- final deterministic sum ----------------
__global__ void final_kernel(const float* __restrict__ part, float* __restrict__ out) {
  float v = part[threadIdx.x];
  float s = wave_sum(v);
  if (threadIdx.x == 0) out[0] = s;
}

extern "C" void kernel_launch(void* const* d_in, const int* in_sizes, int n_in,
                              void* d_out, int out_size, void* d_ws, size_t ws_size,
                              hipStream_t stream) {
  const float* X        = (const float*)d_in[0];
  const float* trans    = (const float*)d_in[1];
  const float* priors   = (const float*)d_in[2];
  const float* means    = (const float*)d_in[3];
  const float* log_vars = (const float*)d_in[4];
  float* ws  = (float*)d_ws;
  float* out = (float*)d_out;

  hipLaunchKernelGGL(setup_kernel, dim3(10), dim3(256), 0, stream,
                     trans, priors, means, log_vars, ws);
  hipLaunchKernelGGL(fused_scan, dim3(4096), dim3(128), 0, stream, X, ws);
  hipLaunchKernelGGL(fwd2_combine, dim3(64), dim3(64), 0, stream, ws);
  hipLaunchKernelGGL(final_kernel, dim3(1), dim3(64), 0, stream,
                     ws + PART_OFF, out);
}

// Round 19
// 112.919 us; speedup vs baseline: 1.5520x; 1.3459x over previous
//
#include <hip/hip_runtime.h>

// HMM forward via chunked parallel scan, EMISSION FUSED INTO SCAN:
// B=64, T=2048, N=64, D=128.  CLEN=64 (r16 structure — best measured).
// Change vs r16: e-tile kept in LDS as F32 (not bf16) — kills the 32
// shift/mask unpack VALU per scan step and the 32 f2bf packs in phase A;
// LDS reads are same-address broadcasts so bandwidth is unchanged.
//
// Math: alpha_t = diag(e_t) * A^T * alpha_{t-1},  e_t[j] = exp(lb_t[j] - m_t).
// fused_scan block (b,cch) [128 thr = 2 waves]:
//   Phase A: wave J computes 32 t-rows of lb = [x^2;x]@Wc + cn (bf16 MFMA,
//     Wc B-frags from global WBF), fused row-max/exp -> e-tile (f32) in LDS
//     + MV (f32, global). Chunk 31's spare slot computes t=0 -> E0G (f32).
//   Phase B: r12-proven bf16 scan: state = 4 bf16 B-frags; per step
//     a = A^T x b (8 asm MFMA, literal-0 C); b' = pack(a*e) fused in cvt_pk
//     (e now a direct f32 register); renorm every 8 steps (exact, into Ls).
// fwd2: per batch fold 32 chunk matrices (G prefetched 1 ahead); per-half
//   scales combined exactly.
//
// B-fragment layout: lane (h=l>>5, il=l&31), frag Kb, word w, half q holds
// B[k][n] with k = 16*Kb + 8*h + 2*w + q, n = 32*J + il.
//
// ws layout (float units):
//   ATF  0        2048     A^T MFMA A-frags (bf16 pairs)
//   PI   2048     64       exp(log_softmax(priors))
//   CN   2112     64       -0.5*(t3 + D*log2pi)
//   WBF  2176     8192     emis Wc B-frags (bf16)
//   MV   10368    131072   m_t per (b,t)
//   PART 141440   64       per-batch final logsumexp
//   GLS  141504   4096     log-scale per (job, J-half)
//   E0G  145600   4096     e at t=0 per batch (f32)
//   G    149696   4194304  (= 8388608 bf16) chunk mats [job][new k][start n]
// total 4344000 floats = 17.4 MB

constexpr int ATF_OFF  = 0;
constexpr int PI_OFF   = 2048;
constexpr int CN_OFF   = 2112;
constexpr int WBF_OFF  = 2176;
constexpr int MV_OFF   = 10368;
constexpr int PART_OFF = 141440;
constexpr int GLS_OFF  = 141504;
constexpr int E0G_OFF  = 145600;
constexpr int G_OFF    = 149696;

typedef __attribute__((ext_vector_type(8))) short bf16x8;
typedef __attribute__((ext_vector_type(4)))  float f32x4;
typedef __attribute__((ext_vector_type(16))) float f32x16;

union BU { unsigned u[4]; bf16x8 v; };

__device__ inline float wave_max(float v) {
  #pragma unroll
  for (int off = 1; off < 64; off <<= 1) v = fmaxf(v, __shfl_xor(v, off));
  return v;
}
__device__ inline float wave_sum(float v) {
  #pragma unroll
  for (int off = 1; off < 64; off <<= 1) v += __shfl_xor(v, off);
  return v;
}
__device__ inline float read_lane(float v, int l) {
  return __uint_as_float(__builtin_amdgcn_readlane(__float_as_uint(v), l));
}
__device__ inline unsigned f2bf(float f) {   // RNE f32->bf16
  unsigned u = __float_as_uint(f);
  u += 0x7FFFu + ((u >> 16) & 1u);
  return u >> 16;
}
__device__ inline unsigned cvt_pk(float lo, float hi) {  // packed f32x2 -> bf16x2
  unsigned r;
  asm("v_cvt_pk_bf16_f32 %0, %1, %2" : "=v"(r) : "v"(lo), "v"(hi));
  return r;
}

// ---------------- setup (merged): blk0 = P/ATF/PI, blk1-8 = WBF, blk9 = CN ----------------
__global__ void setup_kernel(const float* __restrict__ trans,
                             const float* __restrict__ priors,
                             const float* __restrict__ means,
                             const float* __restrict__ log_vars,
                             float* __restrict__ ws) {
  __shared__ float Psh[64 * 64];
  int tid = threadIdx.x, blk = blockIdx.x;

  if (blk == 0) {
    int lane = tid & 63, w = tid >> 6;
    for (int r = 0; r < 16; ++r) {
      int i = w * 16 + r;
      float x = trans[i * 64 + lane];
      float m = wave_max(x);
      float s = wave_sum(__expf(x - m));
      Psh[i * 64 + lane] = __expf(x - (m + __logf(s)));
    }
    if (w == 0) {
      float x = priors[lane];
      float m = wave_max(x);
      float s = wave_sum(__expf(x - m));
      ws[PI_OFF + lane] = __expf(x - (m + __logf(s)));
    }
    __syncthreads();
    // ATF: A-operand frags of A^T, frag f = I*4+Kb; lane l holds
    // A_op[m=32I+(l&31)][k=16Kb+8(l>>5)+j] = P[k][m], j=0..7 packed pairs.
    for (int idx = tid; idx < 512; idx += 256) {
      int f = idx >> 6, l = idx & 63;
      int I = f >> 2, Kb = f & 3;
      int m = 32 * I + (l & 31);
      int kb = 16 * Kb + 8 * (l >> 5);
      unsigned u[4];
      #pragma unroll
      for (int p = 0; p < 4; ++p) {
        unsigned a = f2bf(Psh[(kb + 2 * p) * 64 + m]);
        unsigned b = f2bf(Psh[(kb + 2 * p + 1) * 64 + m]);
        u[p] = a | (b << 16);
      }
      *reinterpret_cast<uint4*>(&ws[ATF_OFF + idx * 4]) = make_uint4(u[0], u[1], u[2], u[3]);
    }
  } else if (blk <= 8) {
    // WBF: B-fragments of Wc. frag (Kb,J), lane l holds
    // B[k=16Kb+8(l>>5)+j][n=32J+(l&31)], j=0..7 packed pairs (even lo).
    int idx = (blk - 1) * 256 + tid;      // 0..2047
    int f = idx >> 6, l = idx & 63;
    int Kb = f >> 1, J = f & 1;
    int n = 32 * J + (l & 31);
    int kb = 16 * Kb + 8 * (l >> 5);
    unsigned u[4];
    #pragma unroll
    for (int p = 0; p < 4; ++p) {
      int k0 = kb + 2 * p, k1 = k0 + 1;
      int d0 = k0 & 127, d1 = k1 & 127;
      float iv0 = __expf(-log_vars[n * 128 + d0]);
      float iv1 = __expf(-log_vars[n * 128 + d1]);
      float a  = (k0 < 128) ? (-0.5f * iv0) : (means[n * 128 + d0] * iv0);
      float bb = (k1 < 128) ? (-0.5f * iv1) : (means[n * 128 + d1] * iv1);
      u[p] = f2bf(a) | (f2bf(bb) << 16);
    }
    *reinterpret_cast<uint4*>(&ws[WBF_OFF + idx * 4]) = make_uint4(u[0], u[1], u[2], u[3]);
  } else {
    // CN: cn[n] = -0.5*(sum_d (mu^2*iv + lv) + D*log(2pi)), 4-way over d
    float* part = Psh;
    int n = tid & 63, g = tid >> 6;
    float s = 0.f;
    for (int d = 32 * g; d < 32 * g + 32; ++d) {
      float lv = log_vars[n * 128 + d];
      float mu = means[n * 128 + d];
      s += mu * mu * __expf(-lv) + lv;
    }
    part[g * 64 + n] = s;
    __syncthreads();
    if (tid < 64) {
      float tot = (part[tid] + part[64 + tid]) + (part[128 + tid] + part[192 + tid]);
      ws[CN_OFF + tid] = -0.5f * (tot + 128.0f * 1.8378770664093453f);
    }
  }
}

// ---------------- fused: emission (phase A) + chunk scan (phase B), CLEN=64 ----------------
__global__ __launch_bounds__(128, 4) void fused_scan(const float* __restrict__ X,
                                                     float* __restrict__ ws) {
  __shared__ __align__(16) float EshF[64 * 64];   // 16 KB e-tile [row][state] f32

  const int tid = threadIdx.x;
  const int lane = tid & 63, J = tid >> 6;   // J = wave id
  const int h = lane >> 5, il = lane & 31;
  const int job = blockIdx.x, b = job >> 5, cch = job & 31;
  const int tstart = 1 + cch * 64;
  const int len = (cch == 31) ? 63 : 64;

  // ================= phase A: emissions for rows 32*J .. 32*J+31 =================
  {
    int i_lane = J * 32 + il;                 // local row this lane's X belongs to
    int t_lane = tstart + i_lane;
    if (cch == 31 && i_lane == 63) t_lane = 0;   // spare slot computes t=0
    const float* Xr = X + ((size_t)b * 2048 + t_lane) * 128;

    bf16x8 ax[8], asq[8];
    #pragma unroll
    for (int s = 0; s < 8; ++s) {
      float4 v0 = *reinterpret_cast<const float4*>(Xr + s * 16 + 8 * h);
      float4 v1 = *reinterpret_cast<const float4*>(Xr + s * 16 + 8 * h + 4);
      BU bx, bq;
      bx.u[0] = cvt_pk(v0.x, v0.y); bx.u[1] = cvt_pk(v0.z, v0.w);
      bx.u[2] = cvt_pk(v1.x, v1.y); bx.u[3] = cvt_pk(v1.z, v1.w);
      bq.u[0] = cvt_pk(v0.x * v0.x, v0.y * v0.y);
      bq.u[1] = cvt_pk(v0.z * v0.z, v0.w * v0.w);
      bq.u[2] = cvt_pk(v1.x * v1.x, v1.y * v1.y);
      bq.u[3] = cvt_pk(v1.z * v1.z, v1.w * v1.w);
      ax[s] = bx.v; asq[s] = bq.v;
    }

    const uint4* wbf = reinterpret_cast<const uint4*>(&ws[WBF_OFF]);
    f32x16 acc0, acc1;
    #pragma unroll
    for (int z = 0; z < 16; ++z) { acc0[z] = 0.f; acc1[z] = 0.f; }
    #pragma unroll
    for (int Kb = 0; Kb < 8; ++Kb) {
      BU b0, b1;
      *reinterpret_cast<uint4*>(b0.u) = wbf[(2 * Kb + 0) * 64 + lane];
      *reinterpret_cast<uint4*>(b1.u) = wbf[(2 * Kb + 1) * 64 + lane];
      acc0 = __builtin_amdgcn_mfma_f32_32x32x16_bf16(asq[Kb], b0.v, acc0, 0, 0, 0);
      acc1 = __builtin_amdgcn_mfma_f32_32x32x16_bf16(asq[Kb], b1.v, acc1, 0, 0, 0);
    }
    #pragma unroll
    for (int Kb = 8; Kb < 16; ++Kb) {
      BU b0, b1;
      *reinterpret_cast<uint4*>(b0.u) = wbf[(2 * Kb + 0) * 64 + lane];
      *reinterpret_cast<uint4*>(b1.u) = wbf[(2 * Kb + 1) * 64 + lane];
      acc0 = __builtin_amdgcn_mfma_f32_32x32x16_bf16(ax[Kb - 8], b0.v, acc0, 0, 0, 0);
      acc1 = __builtin_amdgcn_mfma_f32_32x32x16_bf16(ax[Kb - 8], b1.v, acc1, 0, 0, 0);
    }

    float cn0 = ws[CN_OFF + il];
    float cn1 = ws[CN_OFF + 32 + il];
    float* MVp = &ws[MV_OFF] + (size_t)b * 2048;
    #pragma unroll
    for (int e = 0; e < 16; ++e) {
      float v0 = acc0[e] + cn0;
      float v1 = acc1[e] + cn1;
      float mx = fmaxf(v0, v1);
      #pragma unroll
      for (int off = 1; off < 32; off <<= 1) mx = fmaxf(mx, __shfl_xor(mx, off));
      int r = 32 * J + (e & 3) + 8 * (e >> 2) + 4 * h;   // local row 0..63
      float e0 = __expf(v0 - mx), e1 = __expf(v1 - mx);
      if (cch == 31 && r == 63) {                        // t = 0 special row
        ws[E0G_OFF + b * 64 + il]      = e0;
        ws[E0G_OFF + b * 64 + 32 + il] = e1;
        if (il == 0) MVp[0] = mx;
      } else {
        EshF[r * 64 + il]      = e0;
        EshF[r * 64 + 32 + il] = e1;
        if (il == 0) MVp[tstart + r] = mx;
      }
    }
  }
  __syncthreads();

  // ================= phase B: scan over f32 LDS e-tile =================
  bf16x8 atf0, atf1, atf2, atf3, atf4, atf5, atf6, atf7;
  atf0 = *reinterpret_cast<const bf16x8*>(&ws[ATF_OFF + (0 * 64 + lane) * 4]);
  atf1 = *reinterpret_cast<const bf16x8*>(&ws[ATF_OFF + (1 * 64 + lane) * 4]);
  atf2 = *reinterpret_cast<const bf16x8*>(&ws[ATF_OFF + (2 * 64 + lane) * 4]);
  atf3 = *reinterpret_cast<const bf16x8*>(&ws[ATF_OFF + (3 * 64 + lane) * 4]);
  atf4 = *reinterpret_cast<const bf16x8*>(&ws[ATF_OFF + (4 * 64 + lane) * 4]);
  atf5 = *reinterpret_cast<const bf16x8*>(&ws[ATF_OFF + (5 * 64 + lane) * 4]);
  atf6 = *reinterpret_cast<const bf16x8*>(&ws[ATF_OFF + (6 * 64 + lane) * 4]);
  atf7 = *reinterpret_cast<const bf16x8*>(&ws[ATF_OFF + (7 * 64 + lane) * 4]);

  // identity B-fragments: frag Kb word p half q holds 1.0 iff
  // k = 16Kb+8h+2p+q == 32J+il
  bf16x8 bf0, bf1, bf2, bf3;
  {
    int js0 = 32 * J + il - 8 * h;
#define IDF(dst, Kb) { int js = js0 - 16 * (Kb); BU bu_;                      \
    _Pragma("unroll")                                                         \
    for (int p = 0; p < 4; ++p)                                               \
      bu_.u[p] = ((js >> 1) == p) ? ((js & 1) ? 0x3F800000u : 0x00003F80u) : 0u; \
    dst = bu_.v; }
    IDF(bf0, 0) IDF(bf1, 1) IDF(bf2, 2) IDF(bf3, 3)
#undef IDF
  }

  float Ls = 0.0f;

  // e loads: element z of tile I scales by e[state = 32I + 8(z>>2) + 4h + (z&3)]
  // -> per tile-half: 4 broadcast float4 loads (states 8q+4h .. +3).
#define LOADEF(EL, EH, idx) {                                                 \
    const float* Ep_ = EshF + (size_t)(idx) * 64;                             \
    _Pragma("unroll")                                                         \
    for (int q_ = 0; q_ < 4; ++q_) {                                          \
      EL[q_] = *reinterpret_cast<const f32x4*>(Ep_ + 8 * q_ + 4 * h);         \
      EH[q_] = *reinterpret_cast<const f32x4*>(Ep_ + 32 + 8 * q_ + 4 * h);    \
    } }

  // repack with fused diag(e) scale; EV = e-vector array for this tile
#define BBS(dst, At, p, EV) {                                                 \
    unsigned xe0 = cvt_pk((At)[8*(p)+0] * EV[2*(p)][0],                       \
                          (At)[8*(p)+1] * EV[2*(p)][1]);                      \
    unsigned xe1 = cvt_pk((At)[8*(p)+2] * EV[2*(p)][2],                       \
                          (At)[8*(p)+3] * EV[2*(p)][3]);                      \
    unsigned xo0 = cvt_pk((At)[8*(p)+4] * EV[2*(p)+1][0],                     \
                          (At)[8*(p)+5] * EV[2*(p)+1][1]);                    \
    unsigned xo1 = cvt_pk((At)[8*(p)+6] * EV[2*(p)+1][2],                     \
                          (At)[8*(p)+7] * EV[2*(p)+1][3]);                    \
    asm("v_permlane32_swap_b32 %0, %1" : "+v"(xe0), "+v"(xo0));               \
    asm("v_permlane32_swap_b32 %0, %1" : "+v"(xe1), "+v"(xo1));               \
    BU bu_; bu_.u[0] = xe0; bu_.u[1] = xe1; bu_.u[2] = xo0; bu_.u[3] = xo1;   \
    dst = bu_.v; }

  // MFMA via inline asm; head uses LITERAL 0 as C operand
#define MFMA_HEAD(d, A, B)                                                    \
    asm("v_mfma_f32_32x32x16_bf16 %0, %1, %2, 0"                              \
        : "=&v"(d) : "v"(A), "v"(B));
#define MFMA_ACC(d, A, B)                                                     \
    asm("v_mfma_f32_32x32x16_bf16 %0, %1, %2, %0"                             \
        : "+v"(d) : "v"(A), "v"(B));

#define STEP(EL, EH, DO_RN) {                                                 \
    f32x16 a0, a1;                                                            \
    MFMA_HEAD(a0, atf0, bf0)                                                  \
    MFMA_HEAD(a1, atf4, bf0)                                                  \
    MFMA_ACC(a0, atf1, bf1)                                                   \
    MFMA_ACC(a1, atf5, bf1)                                                   \
    MFMA_ACC(a0, atf2, bf2)                                                   \
    MFMA_ACC(a1, atf6, bf2)                                                   \
    MFMA_ACC(a0, atf3, bf3)                                                   \
    MFMA_ACC(a1, atf7, bf3)                                                   \
    asm volatile("s_nop 7\n\ts_nop 7\n\ts_nop 3" : "+v"(a0), "+v"(a1));       \
    if (DO_RN) {                                                              \
      float mx = 0.f;                                                         \
      _Pragma("unroll")                                                       \
      for (int z = 0; z < 16; ++z) mx = fmaxf(mx, fmaxf(a0[z], a1[z]));       \
      mx = wave_max(mx);                                                      \
      float inv = 1.0f / mx;                                                  \
      Ls += __logf(mx);                                                       \
      _Pragma("unroll")                                                       \
      for (int z = 0; z < 16; ++z) { a0[z] *= inv; a1[z] *= inv; }            \
    }                                                                         \
    BBS(bf0, a0, 0, EL) BBS(bf1, a0, 1, EL)                                   \
    BBS(bf2, a1, 0, EH) BBS(bf3, a1, 1, EH) }

  #pragma unroll 1
  for (int step = 0; step < len; ++step) {
    f32x4 eL[4], eH[4];
    LOADEF(eL, eH, step);
    STEP(eL, eH, ((step & 7) == 7));
  }

#undef STEP
#undef MFMA_ACC
#undef MFMA_HEAD
#undef BBS
#undef LOADEF

  // store G [new k][start n] directly from b-frags (k = 16Kb+8h+2p+q)
  unsigned short* Gb = reinterpret_cast<unsigned short*>(&ws[G_OFF]) + (size_t)job * 4096;
#define GST(fr, Kb) { BU bu_; bu_.v = fr;                                     \
    _Pragma("unroll")                                                         \
    for (int p = 0; p < 4; ++p) {                                             \
      int k = 16 * (Kb) + 8 * h + 2 * p;                                      \
      Gb[k * 64 + 32 * J + il]       = (unsigned short)(bu_.u[p] & 0xFFFFu);  \
      Gb[(k + 1) * 64 + 32 * J + il] = (unsigned short)(bu_.u[p] >> 16);      \
    } }
  GST(bf0, 0) GST(bf1, 1) GST(bf2, 2) GST(bf3, 3)
#undef GST
  if (lane == 0) ws[GLS_OFF + job * 2 + J] = Ls;
}

// ---------------- phase 2: fold 32 chunk matrices per batch (G prefetched) ----------------
__global__ __launch_bounds__(64, 1) void fwd2_combine(float* __restrict__ ws) {
  int b = blockIdx.x, j = threadIdx.x;

  float Ms = 0.f;
  for (int k = 0; k < 32; ++k) Ms += ws[MV_OFF + (size_t)b * 2048 + k * 64 + j];
  Ms = wave_sum(Ms);

  float w = ws[PI_OFF + j] * ws[E0G_OFF + b * 64 + j];   // alpha_0 modulo exp(m_0)
  float Lacc = Ms;

  const unsigned short* Gb =
      reinterpret_cast<const unsigned short*>(&ws[G_OFF]) + (size_t)b * 32 * 4096;
  const uint4* gbase = reinterpret_cast<const uint4*>(Gb);

  uint4 gw[8];
  #pragma unroll
  for (int s = 0; s < 8; ++s) gw[s] = gbase[j * 4 + s];

  for (int c = 0; c < 32; ++c) {
    uint4 gn[8];
    int cnx = (c + 1 < 32) ? (c + 1) : c;
    #pragma unroll
    for (int s = 0; s < 8; ++s) gn[s] = gbase[(size_t)cnx * 256 + j * 4 + s];

    float gv[64];
    #pragma unroll
    for (int s = 0; s < 8; ++s) {
      gv[8 * s + 0] = __uint_as_float(gw[s].x << 16);
      gv[8 * s + 1] = __uint_as_float(gw[s].x & 0xFFFF0000u);
      gv[8 * s + 2] = __uint_as_float(gw[s].y << 16);
      gv[8 * s + 3] = __uint_as_float(gw[s].y & 0xFFFF0000u);
      gv[8 * s + 4] = __uint_as_float(gw[s].z << 16);
      gv[8 * s + 5] = __uint_as_float(gw[s].z & 0xFFFF0000u);
      gv[8 * s + 6] = __uint_as_float(gw[s].w << 16);
      gv[8 * s + 7] = __uint_as_float(gw[s].w & 0xFFFF0000u);
    }
    // split fold: lo (start states 0-31, scale Ls0) / hi (32-63, Ls1)
    float l0 = 0.f, l1 = 0.f, h0 = 0.f, h1 = 0.f;
    #pragma unroll
    for (int i = 0; i < 32; i += 2) {
      l0 = fmaf(read_lane(w, i + 0), gv[i + 0], l0);
      l1 = fmaf(read_lane(w, i + 1), gv[i + 1], l1);
      h0 = fmaf(read_lane(w, 32 + i + 0), gv[32 + i + 0], h0);
      h1 = fmaf(read_lane(w, 32 + i + 1), gv[32 + i + 1], h1);
    }
    float ylo = l0 + l1, yhi = h0 + h1;
    float g0 = ws[GLS_OFF + (b * 32 + c) * 2 + 0];
    float g1 = ws[GLS_OFF + (b * 32 + c) * 2 + 1];
    float Lm = fmaxf(g0, g1);
    float y = __expf(g0 - Lm) * ylo + __expf(g1 - Lm) * yhi;
    float s = wave_sum(y);
    w = y * (1.0f / s);
    Lacc += Lm + __logf(s);

    #pragma unroll
    for (int s2 = 0; s2 < 8; ++s2) gw[s2] = gn[s2];
  }
  float S = wave_sum(w);
  if (j == 0) ws[PART_OFF + b] = Lacc + __logf(S);
}

// ---------------- final deterministic sum ----------------
__global__ void final_kernel(const float* __restrict__ part, float* __restrict__ out) {
  float v = part[threadIdx.x];
  float s = wave_sum(v);
  if (threadIdx.x == 0) out[0] = s;
}

extern "C" void kernel_launch(void* const* d_in, const int* in_sizes, int n_in,
                              void* d_out, int out_size, void* d_ws, size_t ws_size,
                              hipStream_t stream) {
  const float* X        = (const float*)d_in[0];
  const float* trans    = (const float*)d_in[1];
  const float* priors   = (const float*)d_in[2];
  const float* means    = (const float*)d_in[3];
  const float* log_vars = (const float*)d_in[4];
  float* ws  = (float*)d_ws;
  float* out = (float*)d_out;

  hipLaunchKernelGGL(setup_kernel, dim3(10), dim3(256), 0, stream,
                     trans, priors, means, log_vars, ws);
  hipLaunchKernelGGL(fused_scan, dim3(2048), dim3(128), 0, stream, X, ws);
  hipLaunchKernelGGL(fwd2_combine, dim3(64), dim3(64), 0, stream, ws);
  hipLaunchKernelGGL(final_kernel, dim3(1), dim3(64), 0, stream,
                     ws + PART_OFF, out);
}